// Round 12
// baseline (235.564 us; speedup 1.0000x reference)
//
#include <hip/hip_runtime.h>
#include <math.h>

#define B_   2
#define N_   2048
#define D_   1024
#define H_   16
#define HD_  64
#define BH_  32
#define M_   4096   // B_*N_

typedef __bf16 bf16x8 __attribute__((ext_vector_type(8)));
typedef float  f32x4  __attribute__((ext_vector_type(4)));

__device__ inline unsigned short f2b(float f) {
    unsigned u = __float_as_uint(f);
    u += 0x7FFFu + ((u >> 16) & 1u);
    return (unsigned short)(u >> 16);
}
// cheap round (1 ulp vs RNE on ties; P has huge margin)
__device__ inline unsigned short f2b_fast(float f) {
    return (unsigned short)((__float_as_uint(f) + 0x8000u) >> 16);
}

// ---------------------------------------------------------------------------
// Convert x (4096x1024) and Wq/Wk/Wv/Wo (1024x1024 each) fp32 -> bf16 into one
// contiguous ws region: [x | wq | wk | wv | wo].
// ---------------------------------------------------------------------------
__global__ __launch_bounds__(256)
void cvt_all(const float* __restrict__ x,  const float* __restrict__ wq,
             const float* __restrict__ wk, const float* __restrict__ wv,
             const float* __restrict__ wo, ushort* __restrict__ dst)
{
    int i = blockIdx.x * 256 + threadIdx.x;      // float4 index
    if (i >= 2097152) return;                    // (4096*1024 + 4*1024*1024)/4
    int fi = i * 4;
    const float* s; int off;
    if (fi < 4194304) { s = x; off = fi; }
    else {
        int r = fi - 4194304;
        int wsel = r >> 20;                      // each W = 2^20 elements
        off = r & 1048575;
        s = (wsel == 0) ? wq : (wsel == 1) ? wk : (wsel == 2) ? wv : wo;
    }
    float4 f = *(const float4*)(s + off);
    ushort4 o;
    o.x = f2b(f.x); o.y = f2b(f.y); o.z = f2b(f.z); o.w = f2b(f.w);
    *(ushort4*)(dst + fi) = o;
}

// ---------------------------------------------------------------------------
// QKV bf16 MFMA GEMM — R21-verified winner: BK=64, 128x128 tile, 4 waves 2x2,
// reg-prefetch 2-barrier path, 16 barrier-pairs.  LDS [128][72]x2 = 36.9 KB,
// 3 blocks/CU (grid 768 = 3/CU).  (BK=128 would be 69.6 KB -> 2 blocks/CU <
// grid residency = m132 occupancy cliff; do not.)  Total 199.9->190.1 in R11.
// z=0 (Q): scaled by 0.125*log2e (exp2-domain softmax) -> [BH][N][64]
// z=1 (K): [BH][N][64];  z=2 (V): TRANSPOSED [BH][HD][N] (ushort4 stores).
// ---------------------------------------------------------------------------
__global__ __launch_bounds__(256)
void gemm_qkv(const ushort* __restrict__ A,
              const ushort* __restrict__ W0, const ushort* __restrict__ W1,
              const ushort* __restrict__ W2,
              ushort* __restrict__ O0, ushort* __restrict__ O1,
              ushort* __restrict__ O2)
{
    const int z = blockIdx.z;
    const ushort* W = (z == 0) ? W0 : (z == 1) ? W1 : W2;

    __shared__ alignas(16) ushort As[128][72];
    __shared__ alignas(16) ushort Bs[128][72];

    const int t = threadIdx.x;
    const int lane = t & 63, w = t >> 6;
    const int quad = lane >> 4, l15 = lane & 15;
    const int wm = (w >> 1) * 64, wn = (w & 1) * 64;
    const int tileM = blockIdx.x * 128, tileN = blockIdx.y * 128;

    // staging map: rows srow + {0,32,64,96}, ushort cols scol..scol+7
    const int srow = t >> 3;             // 0..31
    const int scol = (t & 7) * 8;        // 0..56
    const ushort* GA = A + (size_t)(tileM + srow) * D_ + scol;
    const ushort* GB = W + (size_t)(tileN + srow) * D_ + scol;

    f32x4 acc[4][4];
#pragma unroll
    for (int mt = 0; mt < 4; ++mt)
#pragma unroll
        for (int nt = 0; nt < 4; ++nt) acc[mt][nt] = (f32x4){0.f, 0.f, 0.f, 0.f};

    uint4 pa0 = *(const uint4*)GA;
    uint4 pa1 = *(const uint4*)(GA + 32 * D_);
    uint4 pa2 = *(const uint4*)(GA + 64 * D_);
    uint4 pa3 = *(const uint4*)(GA + 96 * D_);
    uint4 pb0 = *(const uint4*)GB;
    uint4 pb1 = *(const uint4*)(GB + 32 * D_);
    uint4 pb2 = *(const uint4*)(GB + 64 * D_);
    uint4 pb3 = *(const uint4*)(GB + 96 * D_);

    for (int k0 = 0; k0 < D_; k0 += 64) {
        __syncthreads();                 // prev tile's readers done
        *(uint4*)&As[srow][scol]      = pa0;
        *(uint4*)&As[32 + srow][scol] = pa1;
        *(uint4*)&As[64 + srow][scol] = pa2;
        *(uint4*)&As[96 + srow][scol] = pa3;
        *(uint4*)&Bs[srow][scol]      = pb0;
        *(uint4*)&Bs[32 + srow][scol] = pb1;
        *(uint4*)&Bs[64 + srow][scol] = pb2;
        *(uint4*)&Bs[96 + srow][scol] = pb3;
        __syncthreads();
        if (k0 + 64 < D_) {              // prefetch next tile (used next iter)
            pa0 = *(const uint4*)(GA + k0 + 64);
            pa1 = *(const uint4*)(GA + 32 * D_ + k0 + 64);
            pa2 = *(const uint4*)(GA + 64 * D_ + k0 + 64);
            pa3 = *(const uint4*)(GA + 96 * D_ + k0 + 64);
            pb0 = *(const uint4*)(GB + k0 + 64);
            pb1 = *(const uint4*)(GB + 32 * D_ + k0 + 64);
            pb2 = *(const uint4*)(GB + 64 * D_ + k0 + 64);
            pb3 = *(const uint4*)(GB + 96 * D_ + k0 + 64);
        }

#pragma unroll
        for (int ks = 0; ks < 2; ++ks) {
            bf16x8 af[4], bf[4];
#pragma unroll
            for (int mt = 0; mt < 4; ++mt) af[mt] = *(const bf16x8*)&As[wm + mt * 16 + l15][ks * 32 + quad * 8];
#pragma unroll
            for (int nt = 0; nt < 4; ++nt) bf[nt] = *(const bf16x8*)&Bs[wn + nt * 16 + l15][ks * 32 + quad * 8];
#pragma unroll
            for (int mt = 0; mt < 4; ++mt)
#pragma unroll
                for (int nt = 0; nt < 4; ++nt)
                    acc[mt][nt] = __builtin_amdgcn_mfma_f32_16x16x32_bf16(af[mt], bf[nt], acc[mt][nt], 0, 0, 0);
        }
    }

    ushort* O = (z == 0) ? O0 : (z == 1) ? O1 : O2;
    // Q: fold 1/sqrt(64) AND log2e (exp2-domain softmax) into the scale
    const float scl = (z == 0) ? 0.18033688f : 1.0f;
#pragma unroll
    for (int mt = 0; mt < 4; ++mt)
#pragma unroll
        for (int nt = 0; nt < 4; ++nt) {
            if (z == 2) {
                // V transposed: Vt[bh][dd][n], 4 consecutive n per 8B store
                int rg0 = tileM + wm + mt * 16 + quad * 4;
                int cgc = tileN + wn + nt * 16 + l15;
                int b = rg0 >> 11, n0 = rg0 & (N_ - 1);
                int h = cgc >> 6, dd = cgc & 63;
                ushort4 o4;
                o4.x = f2b(acc[mt][nt][0]); o4.y = f2b(acc[mt][nt][1]);
                o4.z = f2b(acc[mt][nt][2]); o4.w = f2b(acc[mt][nt][3]);
                *(ushort4*)&O[((size_t)((b * H_ + h) * HD_ + dd)) * N_ + n0] = o4;
            } else {
#pragma unroll
                for (int r = 0; r < 4; ++r) {
                    int rg = tileM + wm + mt * 16 + quad * 4 + r;
                    int cgc = tileN + wn + nt * 16 + l15;
                    int b = rg >> 11, n = rg & (N_ - 1);
                    int h = cgc >> 6, dd = cgc & 63;
                    O[(((size_t)(b * H_ + h)) * N_ + n) * HD_ + dd] = f2b(acc[mt][nt][r] * scl);
                }
            }
        }
}

// ---------------------------------------------------------------------------
// Final GEMM — R22: BK=128 (was 64).  fin is GRID-capped at 2 blocks/CU
// (512 blocks) while LDS admitted 3 — headroom that buys no occupancy, so
// spend it on K-depth: As[128][136]+Bs[64][136] = 52.2 KB, still 2 blocks
// resident.  8 barrier-pairs (was 16), 16 MFMA/wave per pair.  Staging:
// rows t>>4 + k*16, cols (t&15)*8 (coalesced 256B rows); [136] stride ->
// ds ops at bank +4 stride = free 2-way.  Prefetch 12x uint4.
// ---------------------------------------------------------------------------
__global__ __launch_bounds__(256)
void gemm_fin(const ushort* __restrict__ A, const ushort* __restrict__ W,
              const float* __restrict__ bias, float* __restrict__ Of)
{
    __shared__ alignas(16) ushort As[128][136];
    __shared__ alignas(16) ushort Bs[64][136];

    const int t = threadIdx.x;
    const int lane = t & 63, w = t >> 6;
    const int quad = lane >> 4, l15 = lane & 15;
    const int wm = (w >> 1) * 64, wn = (w & 1) * 32;
    const int tileM = blockIdx.x * 128, tileN = blockIdx.y * 64;

    const int srow = t >> 4;             // 0..15
    const int scol = (t & 15) * 8;       // 0..120
    const ushort* GA = A + (size_t)(tileM + srow) * D_ + scol;
    const ushort* GB = W + (size_t)(tileN + srow) * D_ + scol;

    f32x4 acc[4][2];
#pragma unroll
    for (int mt = 0; mt < 4; ++mt)
#pragma unroll
        for (int nt = 0; nt < 2; ++nt) acc[mt][nt] = (f32x4){0.f, 0.f, 0.f, 0.f};

    uint4 pa[8], pb[4];
#pragma unroll
    for (int j = 0; j < 8; ++j) pa[j] = *(const uint4*)(GA + (size_t)j * 16 * D_);
#pragma unroll
    for (int j = 0; j < 4; ++j) pb[j] = *(const uint4*)(GB + (size_t)j * 16 * D_);

    for (int k0 = 0; k0 < D_; k0 += 128) {
        __syncthreads();
#pragma unroll
        for (int j = 0; j < 8; ++j) *(uint4*)&As[j * 16 + srow][scol] = pa[j];
#pragma unroll
        for (int j = 0; j < 4; ++j) *(uint4*)&Bs[j * 16 + srow][scol] = pb[j];
        __syncthreads();
        if (k0 + 128 < D_) {
#pragma unroll
            for (int j = 0; j < 8; ++j) pa[j] = *(const uint4*)(GA + (size_t)j * 16 * D_ + k0 + 128);
#pragma unroll
            for (int j = 0; j < 4; ++j) pb[j] = *(const uint4*)(GB + (size_t)j * 16 * D_ + k0 + 128);
        }

#pragma unroll
        for (int ks = 0; ks < 4; ++ks) {
            bf16x8 af[4], bf[2];
#pragma unroll
            for (int mt = 0; mt < 4; ++mt) af[mt] = *(const bf16x8*)&As[wm + mt * 16 + l15][ks * 32 + quad * 8];
#pragma unroll
            for (int nt = 0; nt < 2; ++nt) bf[nt] = *(const bf16x8*)&Bs[wn + nt * 16 + l15][ks * 32 + quad * 8];
#pragma unroll
            for (int mt = 0; mt < 4; ++mt)
#pragma unroll
                for (int nt = 0; nt < 2; ++nt)
                    acc[mt][nt] = __builtin_amdgcn_mfma_f32_16x16x32_bf16(af[mt], bf[nt], acc[mt][nt], 0, 0, 0);
        }
    }

#pragma unroll
    for (int mt = 0; mt < 4; ++mt)
#pragma unroll
        for (int nt = 0; nt < 2; ++nt)
#pragma unroll
            for (int r = 0; r < 4; ++r) {
                int rg = tileM + wm + mt * 16 + quad * 4 + r;
                int cgc = tileN + wn + nt * 16 + l15;
                Of[(size_t)rg * D_ + cgc] = acc[mt][nt][r] + bias[cgc];
            }
}

// ---------------------------------------------------------------------------
// MFMA adaptive-temperature causal flash attention — R3/R20 BYTE-EXACT.
// Verified anchor (63.1-63.9 us).  Ledger: every structural variant regressed
// (R4 224, R5 100, R6 91, R7 92, R8 77, R19 69.5); all components are
// load-bearing.  Do not modify.
// ---------------------------------------------------------------------------
__global__ __launch_bounds__(256)
void attn_mfma(const ushort* __restrict__ Q, const ushort* __restrict__ K,
               const ushort* __restrict__ VT, ushort* __restrict__ AO)
{
    const int bid = blockIdx.x;
    const int qt = 31 - (bid >> 5);     // LPT: heavy q-tiles first
    const int bh = bid & 31;            // bh minor: XCD L2 locality
    const size_t kvbase = (size_t)bh * N_ * HD_;

    __shared__ alignas(16) ushort Ks[128][72];      // [key][hd], 128 keys/stage
    __shared__ alignas(16) ushort Vs[64][136];      // [hd][key], 128 keys + pad
    __shared__ alignas(16) ushort Ps[4][4][296];    // wave-private P, grp-padded

    const int t = threadIdx.x;
    const int lane = t & 63, w = t >> 6;
    const int quad = lane >> 4, l15 = lane & 15;
    const float SH2 = 11.5416913f;     // 8 * log2(e)
    const float LN2 = 0.69314718f;

    // K staging: thread covers rows skey+{0,32,64,96} of the 128-key chunk
    const int skey = t >> 3;            // 0..31
    const int skc  = (t & 7) * 8;       // 0..56
    const ushort* KS = K + kvbase + (size_t)skey * HD_ + skc;   // + key*HD_
    // V staging: thread covers hd rows vhd+{0,16,32,48}, key-cols vkc..vkc+7
    const int vhd = t >> 4;             // 0..15
    const int vkc = (t & 15) * 8;       // 0..120
    const ushort* VS = VT + kvbase + (size_t)vhd * N_ + vkc;    // + chunkbase

    const int qrow = w * 16 + quad * 4;
    const int b = bh >> 4, h = bh & 15;
    const int nCh = (qt + 2) >> 1;      // 128-key chunks (last may be half-used)

    // Q fragments (registers all kernel)
    bf16x8 aq0, aq1;
    {
        const size_t qr = kvbase + (size_t)(qt * 64 + w * 16 + l15) * HD_;
        aq0 = *(const bf16x8*)&Q[qr + quad * 8];
        aq1 = *(const bf16x8*)&Q[qr + 32 + quad * 8];
    }

    float ez[4] = {0.f, 0.f, 0.f, 0.f};
    float sz[4] = {0.f, 0.f, 0.f, 0.f};

    // unmasked pass-1 score tile: accumulate Z, S2
    auto p1_tile = [&](const int nt) {
        f32x4 sv = (f32x4){-SH2, -SH2, -SH2, -SH2};   // C-init: -SH2 rides free
        __builtin_amdgcn_s_setprio(1);
        sv = __builtin_amdgcn_mfma_f32_16x16x32_bf16(aq0, *(const bf16x8*)&Ks[nt * 16 + l15][quad * 8], sv, 0, 0, 0);
        sv = __builtin_amdgcn_mfma_f32_16x16x32_bf16(aq1, *(const bf16x8*)&Ks[nt * 16 + l15][32 + quad * 8], sv, 0, 0, 0);
        __builtin_amdgcn_s_setprio(0);
#pragma unroll
        for (int r = 0; r < 4; ++r) {
            float sh = sv[r];
            float e = __builtin_amdgcn_exp2f(sh);
            ez[r] += e;
            sz[r] = fmaf(e, sh, sz[r]);
        }
    };
    // masked pass-1 tile: j = 16-key offset within the diagonal 64-key block
    auto p1_tile_mask = [&](const int nt, const int j) {
        f32x4 sv = (f32x4){-SH2, -SH2, -SH2, -SH2};
        __builtin_amdgcn_s_setprio(1);
        sv = __builtin_amdgcn_mfma_f32_16x16x32_bf16(aq0, *(const bf16x8*)&Ks[nt * 16 + l15][quad * 8], sv, 0, 0, 0);
        sv = __builtin_amdgcn_mfma_f32_16x16x32_bf16(aq1, *(const bf16x8*)&Ks[nt * 16 + l15][32 + quad * 8], sv, 0, 0, 0);
        __builtin_amdgcn_s_setprio(0);
        const int kc = j * 16 + l15;
#pragma unroll
        for (int r = 0; r < 4; ++r) {
            float sh = sv[r];
            float e = (kc <= qrow + r) ? __builtin_amdgcn_exp2f(sh) : 0.f;
            ez[r] += e;
            sz[r] = fmaf(e, sh, sz[r]);
        }
    };

    // ---------------- pass 1: Z, S2 (128-key stages) ----------------
    uint4 k0 = *(const uint4*)KS;
    uint4 k1 = *(const uint4*)(KS + 32 * HD_);
    uint4 k2 = *(const uint4*)(KS + 64 * HD_);
    uint4 k3 = *(const uint4*)(KS + 96 * HD_);
    const int nF1 = nCh - 1;            // fully-unmasked chunks
    for (int c = 0; c < nF1; ++c) {
        __syncthreads();
        *(uint4*)&Ks[skey][skc]      = k0;
        *(uint4*)&Ks[32 + skey][skc] = k1;
        *(uint4*)&Ks[64 + skey][skc] = k2;
        *(uint4*)&Ks[96 + skey][skc] = k3;
        __syncthreads();
        {   // prefetch chunk c+1 (always exists: c+1 <= nCh-1)
            const ushort* nb = KS + (size_t)(c + 1) * (128 * HD_);
            k0 = *(const uint4*)nb;
            k1 = *(const uint4*)(nb + 32 * HD_);
            k2 = *(const uint4*)(nb + 64 * HD_);
            k3 = *(const uint4*)(nb + 96 * HD_);
        }
#pragma unroll
        for (int nt = 0; nt < 8; ++nt) p1_tile(nt);
    }
    // final chunk: qt odd -> 4 unmasked + 4 masked tiles; qt even -> 4 masked
    __syncthreads();
    *(uint4*)&Ks[skey][skc]      = k0;
    *(uint4*)&Ks[32 + skey][skc] = k1;
    *(uint4*)&Ks[64 + skey][skc] = k2;
    *(uint4*)&Ks[96 + skey][skc] = k3;
    __syncthreads();
    if (qt & 1) {
#pragma unroll
        for (int nt = 0; nt < 4; ++nt) p1_tile(nt);
#pragma unroll
        for (int j = 0; j < 4; ++j) p1_tile_mask(4 + j, j);
    } else {
#pragma unroll
        for (int j = 0; j < 4; ++j) p1_tile_mask(j, j);
    }

    // hoisted 16-lane butterfly reduce
#pragma unroll
    for (int r = 0; r < 4; ++r) {
#pragma unroll
        for (int off = 1; off < 16; off <<= 1) {
            ez[r] += __shfl_xor(ez[r], off);
            sz[r] += __shfl_xor(sz[r], off);
        }
    }

    // ---------------- entropy -> beta ----------------
    float bl[4];   // w = exp2(beta * (s2 - SH2))  (sv carries -SH2)
#pragma unroll
    for (int r = 0; r < 4; ++r) {
        float Z = ez[r];
        float Hh = LN2 * (__builtin_amdgcn_logf(Z) - sz[r] / Z);
        float bb = 1.f;
        if (Hh > 0.5f) {
            float e2 = Hh * Hh;
            float pp = -0.037f * e2 * e2 + 0.481f * e2 * Hh - 2.3f * e2 + 4.917f * Hh - 1.791f;
            bb = fmaxf(pp, 1.f);
        }
        bl[r] = bb;
    }

    // ---------------- pass 2: O, Z' (128-key stages, two 64-key halves) -----
    f32x4 ov[4];
#pragma unroll
    for (int nt = 0; nt < 4; ++nt) ov[nt] = (f32x4){0.f, 0.f, 0.f, 0.f};
    float zp[4] = {0.f, 0.f, 0.f, 0.f};

    // one 64-key half: QK^T -> weights -> P round-trip -> PV
    auto do_half = [&](const int hh, const bool diag) {
        float wv[4][4];
#pragma unroll
        for (int nt = 0; nt < 4; ++nt) {
            f32x4 sv = (f32x4){-SH2, -SH2, -SH2, -SH2};   // C-init: -SH2
            __builtin_amdgcn_s_setprio(1);
            sv = __builtin_amdgcn_mfma_f32_16x16x32_bf16(aq0, *(const bf16x8*)&Ks[hh * 64 + nt * 16 + l15][quad * 8], sv, 0, 0, 0);
            sv = __builtin_amdgcn_mfma_f32_16x16x32_bf16(aq1, *(const bf16x8*)&Ks[hh * 64 + nt * 16 + l15][32 + quad * 8], sv, 0, 0, 0);
            __builtin_amdgcn_s_setprio(0);
#pragma unroll
            for (int r = 0; r < 4; ++r) {
                float e = __builtin_amdgcn_exp2f(bl[r] * sv[r]);
                wv[nt][r] = (!diag || (nt * 16 + l15 <= qrow + r)) ? e : 0.f;
            }
        }
        // P -> wave-private LDS (C-layout write, A-layout read; same-wave)
#pragma unroll
        for (int nt = 0; nt < 4; ++nt)
#pragma unroll
            for (int r = 0; r < 4; ++r)
                Ps[w][quad][r * 72 + nt * 16 + l15] = f2b_fast(wv[nt][r]);
#pragma unroll
        for (int r = 0; r < 4; ++r)
            zp[r] += (wv[0][r] + wv[1][r]) + (wv[2][r] + wv[3][r]);

        bf16x8 pa0 = *(const bf16x8*)&Ps[w][l15 >> 2][(l15 & 3) * 72 + quad * 8];
        bf16x8 pa1 = *(const bf16x8*)&Ps[w][l15 >> 2][(l15 & 3) * 72 + 32 + quad * 8];
#pragma unroll
        for (int nt = 0; nt < 4; ++nt) {
            __builtin_amdgcn_s_setprio(1);
            ov[nt] = __builtin_amdgcn_mfma_f32_16x16x32_bf16(pa0, *(const bf16x8*)&Vs[nt * 16 + l15][hh * 64 + quad * 8], ov[nt], 0, 0, 0);
            ov[nt] = __builtin_amdgcn_mfma_f32_16x16x32_bf16(pa1, *(const bf16x8*)&Vs[nt * 16 + l15][hh * 64 + 32 + quad * 8], ov[nt], 0, 0, 0);
            __builtin_amdgcn_s_setprio(0);
        }
    };

    k0 = *(const uint4*)KS;
    k1 = *(const uint4*)(KS + 32 * HD_);
    k2 = *(const uint4*)(KS + 64 * HD_);
    k3 = *(const uint4*)(KS + 96 * HD_);
    uint4 v0 = *(const uint4*)VS;
    uint4 v1 = *(const uint4*)(VS + 16 * N_);
    uint4 v2 = *(const uint4*)(VS + 32 * N_);
    uint4 v3 = *(const uint4*)(VS + 48 * N_);

    const int nFull = qt >> 1;          // chunks with both halves unmasked
    for (int c = 0; c < nFull; ++c) {
        __syncthreads();
        *(uint4*)&Ks[skey][skc]      = k0;
        *(uint4*)&Ks[32 + skey][skc] = k1;
        *(uint4*)&Ks[64 + skey][skc] = k2;
        *(uint4*)&Ks[96 + skey][skc] = k3;
        *(uint4*)&Vs[vhd][vkc]       = v0;
        *(uint4*)&Vs[16 + vhd][vkc]  = v1;
        *(uint4*)&Vs[32 + vhd][vkc]  = v2;
        *(uint4*)&Vs[48 + vhd][vkc]  = v3;
        __syncthreads();
        {   // prefetch chunk c+1 (always exists: c+1 <= nFull = nCh-1)
            const ushort* nk = KS + (size_t)(c + 1) * (128 * HD_);
            k0 = *(const uint4*)nk;
            k1 = *(const uint4*)(nk + 32 * HD_);
            k2 = *(const uint4*)(nk + 64 * HD_);
            k3 = *(const uint4*)(nk + 96 * HD_);
            const ushort* nv = VS + (c + 1) * 128;
            v0 = *(const uint4*)nv;
            v1 = *(const uint4*)(nv + 16 * N_);
            v2 = *(const uint4*)(nv + 32 * N_);
            v3 = *(const uint4*)(nv + 48 * N_);
        }
        do_half(0, false);
        do_half(1, false);
    }
    // final chunk: diagonal half (+ preceding unmasked half if qt odd)
    __syncthreads();
    *(uint4*)&Ks[skey][skc]      = k0;
    *(uint4*)&Ks[32 + skey][skc] = k1;
    *(uint4*)&Ks[64 + skey][skc] = k2;
    *(uint4*)&Ks[96 + skey][skc] = k3;
    *(uint4*)&Vs[vhd][vkc]       = v0;
    *(uint4*)&Vs[16 + vhd][vkc]  = v1;
    *(uint4*)&Vs[32 + vhd][vkc]  = v2;
    *(uint4*)&Vs[48 + vhd][vkc]  = v3;
    __syncthreads();
    if (qt & 1) {
        do_half(0, false);
        do_half(1, true);
    } else {
        do_half(0, true);
    }

    // hoisted Z' butterfly
#pragma unroll
    for (int r = 0; r < 4; ++r)
#pragma unroll
        for (int off = 1; off < 16; off <<= 1) zp[r] += __shfl_xor(zp[r], off);

    // ---------------- write AO [B, N, D] bf16 ----------------
#pragma unroll
    for (int r = 0; r < 4; ++r) {
        int qg = qt * 64 + w * 16 + quad * 4 + r;
        float inv = 1.f / zp[r];
        size_t rowoff = ((size_t)(b * N_ + qg)) * D_ + h * HD_;
#pragma unroll
        for (int nt = 0; nt < 4; ++nt)
            AO[rowoff + nt * 16 + l15] = f2b(ov[nt][r] * inv);
    }
}

// ---------------------------------------------------------------------------
extern "C" void kernel_launch(void* const* d_in, const int* in_sizes, int n_in,
                              void* d_out, int out_size, void* d_ws, size_t ws_size,
                              hipStream_t stream)
{
    const float* x  = (const float*)d_in[0];
    const float* Wq = (const float*)d_in[1];
    const float* Wk = (const float*)d_in[2];
    const float* Wv = (const float*)d_in[3];
    const float* Wo = (const float*)d_in[4];
    const float* bo = (const float*)d_in[5];
    float* out = (float*)d_out;

    ushort* ws  = (ushort*)d_ws;
    ushort* xb  = ws;                       // 4096*1024
    ushort* wqb = ws + 4194304;             // 1024*1024 each
    ushort* wkb = ws + 5242880;
    ushort* wvb = ws + 6291456;
    ushort* wob = ws + 7340032;
    ushort* Qb  = ws + 8388608;             // [32][2048][64]
    ushort* Kb  = ws + 12582912;            // [32][2048][64]
    ushort* Vtb = ws + 16777216;            // [32][64][2048]  (transposed V)
    ushort* aob = ws + 20971520;            // 4096*1024

    cvt_all<<<8192, 256, 0, stream>>>(x, Wq, Wk, Wv, Wo, xb);

    gemm_qkv<<<dim3(32, 8, 3), 256, 0, stream>>>(
        xb, wqb, wkb, wvb, Qb, Kb, Vtb);

    attn_mfma<<<dim3(1024), 256, 0, stream>>>(Qb, Kb, Vtb, aob);

    gemm_fin<<<dim3(32, 16), 256, 0, stream>>>(aob, wob, bo, out);
}

// Round 13
// 190.764 us; speedup vs baseline: 1.2348x; 1.2348x over previous
//
#include <hip/hip_runtime.h>
#include <math.h>

#define B_   2
#define N_   2048
#define D_   1024
#define H_   16
#define HD_  64
#define BH_  32
#define M_   4096   // B_*N_

typedef __bf16 bf16x8 __attribute__((ext_vector_type(8)));
typedef float  f32x4  __attribute__((ext_vector_type(4)));

__device__ inline unsigned short f2b(float f) {
    unsigned u = __float_as_uint(f);
    u += 0x7FFFu + ((u >> 16) & 1u);
    return (unsigned short)(u >> 16);
}
// cheap round (1 ulp vs RNE on ties; P has huge margin)
__device__ inline unsigned short f2b_fast(float f) {
    return (unsigned short)((__float_as_uint(f) + 0x8000u) >> 16);
}

// ---------------------------------------------------------------------------
// Convert x (4096x1024) and Wq/Wk/Wv/Wo (1024x1024 each) fp32 -> bf16 into one
// contiguous ws region: [x | wq | wk | wv | wo].
// ---------------------------------------------------------------------------
__global__ __launch_bounds__(256)
void cvt_all(const float* __restrict__ x,  const float* __restrict__ wq,
             const float* __restrict__ wk, const float* __restrict__ wv,
             const float* __restrict__ wo, ushort* __restrict__ dst)
{
    int i = blockIdx.x * 256 + threadIdx.x;      // float4 index
    if (i >= 2097152) return;                    // (4096*1024 + 4*1024*1024)/4
    int fi = i * 4;
    const float* s; int off;
    if (fi < 4194304) { s = x; off = fi; }
    else {
        int r = fi - 4194304;
        int wsel = r >> 20;                      // each W = 2^20 elements
        off = r & 1048575;
        s = (wsel == 0) ? wq : (wsel == 1) ? wk : (wsel == 2) ? wv : wo;
    }
    float4 f = *(const float4*)(s + off);
    ushort4 o;
    o.x = f2b(f.x); o.y = f2b(f.y); o.z = f2b(f.z); o.w = f2b(f.w);
    *(ushort4*)(dst + fi) = o;
}

// ---------------------------------------------------------------------------
// QKV bf16 MFMA GEMM — R21-verified winner: BK=64, 128x128 tile, 4 waves 2x2,
// reg-prefetch 2-barrier path, 16 barrier-pairs.  LDS [128][72]x2 = 36.9 KB,
// 3 blocks/CU.  Total 199.9->190.1 in R11.
// z=0 (Q): scaled by 0.125*log2e (exp2-domain softmax) -> [BH][N][64]
// z=1 (K): [BH][N][64];  z=2 (V): TRANSPOSED [BH][HD][N] (ushort4 stores).
// ---------------------------------------------------------------------------
__global__ __launch_bounds__(256)
void gemm_qkv(const ushort* __restrict__ A,
              const ushort* __restrict__ W0, const ushort* __restrict__ W1,
              const ushort* __restrict__ W2,
              ushort* __restrict__ O0, ushort* __restrict__ O1,
              ushort* __restrict__ O2)
{
    const int z = blockIdx.z;
    const ushort* W = (z == 0) ? W0 : (z == 1) ? W1 : W2;

    __shared__ alignas(16) ushort As[128][72];
    __shared__ alignas(16) ushort Bs[128][72];

    const int t = threadIdx.x;
    const int lane = t & 63, w = t >> 6;
    const int quad = lane >> 4, l15 = lane & 15;
    const int wm = (w >> 1) * 64, wn = (w & 1) * 64;
    const int tileM = blockIdx.x * 128, tileN = blockIdx.y * 128;

    // staging map: rows srow + {0,32,64,96}, ushort cols scol..scol+7
    const int srow = t >> 3;             // 0..31
    const int scol = (t & 7) * 8;        // 0..56
    const ushort* GA = A + (size_t)(tileM + srow) * D_ + scol;
    const ushort* GB = W + (size_t)(tileN + srow) * D_ + scol;

    f32x4 acc[4][4];
#pragma unroll
    for (int mt = 0; mt < 4; ++mt)
#pragma unroll
        for (int nt = 0; nt < 4; ++nt) acc[mt][nt] = (f32x4){0.f, 0.f, 0.f, 0.f};

    uint4 pa0 = *(const uint4*)GA;
    uint4 pa1 = *(const uint4*)(GA + 32 * D_);
    uint4 pa2 = *(const uint4*)(GA + 64 * D_);
    uint4 pa3 = *(const uint4*)(GA + 96 * D_);
    uint4 pb0 = *(const uint4*)GB;
    uint4 pb1 = *(const uint4*)(GB + 32 * D_);
    uint4 pb2 = *(const uint4*)(GB + 64 * D_);
    uint4 pb3 = *(const uint4*)(GB + 96 * D_);

    for (int k0 = 0; k0 < D_; k0 += 64) {
        __syncthreads();                 // prev tile's readers done
        *(uint4*)&As[srow][scol]      = pa0;
        *(uint4*)&As[32 + srow][scol] = pa1;
        *(uint4*)&As[64 + srow][scol] = pa2;
        *(uint4*)&As[96 + srow][scol] = pa3;
        *(uint4*)&Bs[srow][scol]      = pb0;
        *(uint4*)&Bs[32 + srow][scol] = pb1;
        *(uint4*)&Bs[64 + srow][scol] = pb2;
        *(uint4*)&Bs[96 + srow][scol] = pb3;
        __syncthreads();
        if (k0 + 64 < D_) {              // prefetch next tile (used next iter)
            pa0 = *(const uint4*)(GA + k0 + 64);
            pa1 = *(const uint4*)(GA + 32 * D_ + k0 + 64);
            pa2 = *(const uint4*)(GA + 64 * D_ + k0 + 64);
            pa3 = *(const uint4*)(GA + 96 * D_ + k0 + 64);
            pb0 = *(const uint4*)(GB + k0 + 64);
            pb1 = *(const uint4*)(GB + 32 * D_ + k0 + 64);
            pb2 = *(const uint4*)(GB + 64 * D_ + k0 + 64);
            pb3 = *(const uint4*)(GB + 96 * D_ + k0 + 64);
        }

#pragma unroll
        for (int ks = 0; ks < 2; ++ks) {
            bf16x8 af[4], bf[4];
#pragma unroll
            for (int mt = 0; mt < 4; ++mt) af[mt] = *(const bf16x8*)&As[wm + mt * 16 + l15][ks * 32 + quad * 8];
#pragma unroll
            for (int nt = 0; nt < 4; ++nt) bf[nt] = *(const bf16x8*)&Bs[wn + nt * 16 + l15][ks * 32 + quad * 8];
#pragma unroll
            for (int mt = 0; mt < 4; ++mt)
#pragma unroll
                for (int nt = 0; nt < 4; ++nt)
                    acc[mt][nt] = __builtin_amdgcn_mfma_f32_16x16x32_bf16(af[mt], bf[nt], acc[mt][nt], 0, 0, 0);
        }
    }

    ushort* O = (z == 0) ? O0 : (z == 1) ? O1 : O2;
    // Q: fold 1/sqrt(64) AND log2e (exp2-domain softmax) into the scale
    const float scl = (z == 0) ? 0.18033688f : 1.0f;
#pragma unroll
    for (int mt = 0; mt < 4; ++mt)
#pragma unroll
        for (int nt = 0; nt < 4; ++nt) {
            if (z == 2) {
                // V transposed: Vt[bh][dd][n], 4 consecutive n per 8B store
                int rg0 = tileM + wm + mt * 16 + quad * 4;
                int cgc = tileN + wn + nt * 16 + l15;
                int b = rg0 >> 11, n0 = rg0 & (N_ - 1);
                int h = cgc >> 6, dd = cgc & 63;
                ushort4 o4;
                o4.x = f2b(acc[mt][nt][0]); o4.y = f2b(acc[mt][nt][1]);
                o4.z = f2b(acc[mt][nt][2]); o4.w = f2b(acc[mt][nt][3]);
                *(ushort4*)&O[((size_t)((b * H_ + h) * HD_ + dd)) * N_ + n0] = o4;
            } else {
#pragma unroll
                for (int r = 0; r < 4; ++r) {
                    int rg = tileM + wm + mt * 16 + quad * 4 + r;
                    int cgc = tileN + wn + nt * 16 + l15;
                    int b = rg >> 11, n = rg & (N_ - 1);
                    int h = cgc >> 6, dd = cgc & 63;
                    O[(((size_t)(b * H_ + h)) * N_ + n) * HD_ + dd] = f2b(acc[mt][nt][r] * scl);
                }
            }
        }
}

// ---------------------------------------------------------------------------
// Final GEMM — R21-verified: BK=64.  128x64 tile, 4 waves 2x2, each 64x32;
// reg-prefetch 2-barrier path, 16 barrier-pairs.  LDS As[128][72]+Bs[64][72]
// = 27.6 KB.  R22 lesson: BK=128 with uint4 pa[8]/pb[4] arrays spilled to
// scratch (WRITE_SIZE 150 MB vs 16 MB output, VGPR 68, fin 8.6->67us) —
// rule #20: the allocator put the deep prefetch arrays in local memory.
// Named scalars + BK=64 is the verified form; do not deepen.
// ---------------------------------------------------------------------------
__global__ __launch_bounds__(256)
void gemm_fin(const ushort* __restrict__ A, const ushort* __restrict__ W,
              const float* __restrict__ bias, float* __restrict__ Of)
{
    __shared__ alignas(16) ushort As[128][72];
    __shared__ alignas(16) ushort Bs[64][72];

    const int t = threadIdx.x;
    const int lane = t & 63, w = t >> 6;
    const int quad = lane >> 4, l15 = lane & 15;
    const int wm = (w >> 1) * 64, wn = (w & 1) * 32;
    const int tileM = blockIdx.x * 128, tileN = blockIdx.y * 64;

    const int srow = t >> 3;             // 0..31
    const int scol = (t & 7) * 8;        // 0..56
    const ushort* GA = A + (size_t)(tileM + srow) * D_ + scol;
    const ushort* GB = W + (size_t)(tileN + srow) * D_ + scol;

    f32x4 acc[4][2];
#pragma unroll
    for (int mt = 0; mt < 4; ++mt)
#pragma unroll
        for (int nt = 0; nt < 2; ++nt) acc[mt][nt] = (f32x4){0.f, 0.f, 0.f, 0.f};

    uint4 pa0 = *(const uint4*)GA;
    uint4 pa1 = *(const uint4*)(GA + 32 * D_);
    uint4 pa2 = *(const uint4*)(GA + 64 * D_);
    uint4 pa3 = *(const uint4*)(GA + 96 * D_);
    uint4 pb0 = *(const uint4*)GB;
    uint4 pb1 = *(const uint4*)(GB + 32 * D_);

    for (int k0 = 0; k0 < D_; k0 += 64) {
        __syncthreads();
        *(uint4*)&As[srow][scol]      = pa0;
        *(uint4*)&As[32 + srow][scol] = pa1;
        *(uint4*)&As[64 + srow][scol] = pa2;
        *(uint4*)&As[96 + srow][scol] = pa3;
        *(uint4*)&Bs[srow][scol]      = pb0;
        *(uint4*)&Bs[32 + srow][scol] = pb1;
        __syncthreads();
        if (k0 + 64 < D_) {
            pa0 = *(const uint4*)(GA + k0 + 64);
            pa1 = *(const uint4*)(GA + 32 * D_ + k0 + 64);
            pa2 = *(const uint4*)(GA + 64 * D_ + k0 + 64);
            pa3 = *(const uint4*)(GA + 96 * D_ + k0 + 64);
            pb0 = *(const uint4*)(GB + k0 + 64);
            pb1 = *(const uint4*)(GB + 32 * D_ + k0 + 64);
        }

#pragma unroll
        for (int ks = 0; ks < 2; ++ks) {
            bf16x8 af[4], bf[2];
#pragma unroll
            for (int mt = 0; mt < 4; ++mt) af[mt] = *(const bf16x8*)&As[wm + mt * 16 + l15][ks * 32 + quad * 8];
#pragma unroll
            for (int nt = 0; nt < 2; ++nt) bf[nt] = *(const bf16x8*)&Bs[wn + nt * 16 + l15][ks * 32 + quad * 8];
#pragma unroll
            for (int mt = 0; mt < 4; ++mt)
#pragma unroll
                for (int nt = 0; nt < 2; ++nt)
                    acc[mt][nt] = __builtin_amdgcn_mfma_f32_16x16x32_bf16(af[mt], bf[nt], acc[mt][nt], 0, 0, 0);
        }
    }

#pragma unroll
    for (int mt = 0; mt < 4; ++mt)
#pragma unroll
        for (int nt = 0; nt < 2; ++nt)
#pragma unroll
            for (int r = 0; r < 4; ++r) {
                int rg = tileM + wm + mt * 16 + quad * 4 + r;
                int cgc = tileN + wn + nt * 16 + l15;
                Of[(size_t)rg * D_ + cgc] = acc[mt][nt][r] + bias[cgc];
            }
}

// ---------------------------------------------------------------------------
// MFMA adaptive-temperature causal flash attention — R3/R20 BYTE-EXACT.
// Verified anchor (63.1-63.9 us).  Ledger: every structural variant regressed
// (R4 224, R5 100, R6 91, R7 92, R8 77, R19 69.5); all components are
// load-bearing.  Do not modify.
// ---------------------------------------------------------------------------
__global__ __launch_bounds__(256)
void attn_mfma(const ushort* __restrict__ Q, const ushort* __restrict__ K,
               const ushort* __restrict__ VT, ushort* __restrict__ AO)
{
    const int bid = blockIdx.x;
    const int qt = 31 - (bid >> 5);     // LPT: heavy q-tiles first
    const int bh = bid & 31;            // bh minor: XCD L2 locality
    const size_t kvbase = (size_t)bh * N_ * HD_;

    __shared__ alignas(16) ushort Ks[128][72];      // [key][hd], 128 keys/stage
    __shared__ alignas(16) ushort Vs[64][136];      // [hd][key], 128 keys + pad
    __shared__ alignas(16) ushort Ps[4][4][296];    // wave-private P, grp-padded

    const int t = threadIdx.x;
    const int lane = t & 63, w = t >> 6;
    const int quad = lane >> 4, l15 = lane & 15;
    const float SH2 = 11.5416913f;     // 8 * log2(e)
    const float LN2 = 0.69314718f;

    // K staging: thread covers rows skey+{0,32,64,96} of the 128-key chunk
    const int skey = t >> 3;            // 0..31
    const int skc  = (t & 7) * 8;       // 0..56
    const ushort* KS = K + kvbase + (size_t)skey * HD_ + skc;   // + key*HD_
    // V staging: thread covers hd rows vhd+{0,16,32,48}, key-cols vkc..vkc+7
    const int vhd = t >> 4;             // 0..15
    const int vkc = (t & 15) * 8;       // 0..120
    const ushort* VS = VT + kvbase + (size_t)vhd * N_ + vkc;    // + chunkbase

    const int qrow = w * 16 + quad * 4;
    const int b = bh >> 4, h = bh & 15;
    const int nCh = (qt + 2) >> 1;      // 128-key chunks (last may be half-used)

    // Q fragments (registers all kernel)
    bf16x8 aq0, aq1;
    {
        const size_t qr = kvbase + (size_t)(qt * 64 + w * 16 + l15) * HD_;
        aq0 = *(const bf16x8*)&Q[qr + quad * 8];
        aq1 = *(const bf16x8*)&Q[qr + 32 + quad * 8];
    }

    float ez[4] = {0.f, 0.f, 0.f, 0.f};
    float sz[4] = {0.f, 0.f, 0.f, 0.f};

    // unmasked pass-1 score tile: accumulate Z, S2
    auto p1_tile = [&](const int nt) {
        f32x4 sv = (f32x4){-SH2, -SH2, -SH2, -SH2};   // C-init: -SH2 rides free
        __builtin_amdgcn_s_setprio(1);
        sv = __builtin_amdgcn_mfma_f32_16x16x32_bf16(aq0, *(const bf16x8*)&Ks[nt * 16 + l15][quad * 8], sv, 0, 0, 0);
        sv = __builtin_amdgcn_mfma_f32_16x16x32_bf16(aq1, *(const bf16x8*)&Ks[nt * 16 + l15][32 + quad * 8], sv, 0, 0, 0);
        __builtin_amdgcn_s_setprio(0);
#pragma unroll
        for (int r = 0; r < 4; ++r) {
            float sh = sv[r];
            float e = __builtin_amdgcn_exp2f(sh);
            ez[r] += e;
            sz[r] = fmaf(e, sh, sz[r]);
        }
    };
    // masked pass-1 tile: j = 16-key offset within the diagonal 64-key block
    auto p1_tile_mask = [&](const int nt, const int j) {
        f32x4 sv = (f32x4){-SH2, -SH2, -SH2, -SH2};
        __builtin_amdgcn_s_setprio(1);
        sv = __builtin_amdgcn_mfma_f32_16x16x32_bf16(aq0, *(const bf16x8*)&Ks[nt * 16 + l15][quad * 8], sv, 0, 0, 0);
        sv = __builtin_amdgcn_mfma_f32_16x16x32_bf16(aq1, *(const bf16x8*)&Ks[nt * 16 + l15][32 + quad * 8], sv, 0, 0, 0);
        __builtin_amdgcn_s_setprio(0);
        const int kc = j * 16 + l15;
#pragma unroll
        for (int r = 0; r < 4; ++r) {
            float sh = sv[r];
            float e = (kc <= qrow + r) ? __builtin_amdgcn_exp2f(sh) : 0.f;
            ez[r] += e;
            sz[r] = fmaf(e, sh, sz[r]);
        }
    };

    // ---------------- pass 1: Z, S2 (128-key stages) ----------------
    uint4 k0 = *(const uint4*)KS;
    uint4 k1 = *(const uint4*)(KS + 32 * HD_);
    uint4 k2 = *(const uint4*)(KS + 64 * HD_);
    uint4 k3 = *(const uint4*)(KS + 96 * HD_);
    const int nF1 = nCh - 1;            // fully-unmasked chunks
    for (int c = 0; c < nF1; ++c) {
        __syncthreads();
        *(uint4*)&Ks[skey][skc]      = k0;
        *(uint4*)&Ks[32 + skey][skc] = k1;
        *(uint4*)&Ks[64 + skey][skc] = k2;
        *(uint4*)&Ks[96 + skey][skc] = k3;
        __syncthreads();
        {   // prefetch chunk c+1 (always exists: c+1 <= nCh-1)
            const ushort* nb = KS + (size_t)(c + 1) * (128 * HD_);
            k0 = *(const uint4*)nb;
            k1 = *(const uint4*)(nb + 32 * HD_);
            k2 = *(const uint4*)(nb + 64 * HD_);
            k3 = *(const uint4*)(nb + 96 * HD_);
        }
#pragma unroll
        for (int nt = 0; nt < 8; ++nt) p1_tile(nt);
    }
    // final chunk: qt odd -> 4 unmasked + 4 masked tiles; qt even -> 4 masked
    __syncthreads();
    *(uint4*)&Ks[skey][skc]      = k0;
    *(uint4*)&Ks[32 + skey][skc] = k1;
    *(uint4*)&Ks[64 + skey][skc] = k2;
    *(uint4*)&Ks[96 + skey][skc] = k3;
    __syncthreads();
    if (qt & 1) {
#pragma unroll
        for (int nt = 0; nt < 4; ++nt) p1_tile(nt);
#pragma unroll
        for (int j = 0; j < 4; ++j) p1_tile_mask(4 + j, j);
    } else {
#pragma unroll
        for (int j = 0; j < 4; ++j) p1_tile_mask(j, j);
    }

    // hoisted 16-lane butterfly reduce
#pragma unroll
    for (int r = 0; r < 4; ++r) {
#pragma unroll
        for (int off = 1; off < 16; off <<= 1) {
            ez[r] += __shfl_xor(ez[r], off);
            sz[r] += __shfl_xor(sz[r], off);
        }
    }

    // ---------------- entropy -> beta ----------------
    float bl[4];   // w = exp2(beta * (s2 - SH2))  (sv carries -SH2)
#pragma unroll
    for (int r = 0; r < 4; ++r) {
        float Z = ez[r];
        float Hh = LN2 * (__builtin_amdgcn_logf(Z) - sz[r] / Z);
        float bb = 1.f;
        if (Hh > 0.5f) {
            float e2 = Hh * Hh;
            float pp = -0.037f * e2 * e2 + 0.481f * e2 * Hh - 2.3f * e2 + 4.917f * Hh - 1.791f;
            bb = fmaxf(pp, 1.f);
        }
        bl[r] = bb;
    }

    // ---------------- pass 2: O, Z' (128-key stages, two 64-key halves) -----
    f32x4 ov[4];
#pragma unroll
    for (int nt = 0; nt < 4; ++nt) ov[nt] = (f32x4){0.f, 0.f, 0.f, 0.f};
    float zp[4] = {0.f, 0.f, 0.f, 0.f};

    // one 64-key half: QK^T -> weights -> P round-trip -> PV
    auto do_half = [&](const int hh, const bool diag) {
        float wv[4][4];
#pragma unroll
        for (int nt = 0; nt < 4; ++nt) {
            f32x4 sv = (f32x4){-SH2, -SH2, -SH2, -SH2};   // C-init: -SH2
            __builtin_amdgcn_s_setprio(1);
            sv = __builtin_amdgcn_mfma_f32_16x16x32_bf16(aq0, *(const bf16x8*)&Ks[hh * 64 + nt * 16 + l15][quad * 8], sv, 0, 0, 0);
            sv = __builtin_amdgcn_mfma_f32_16x16x32_bf16(aq1, *(const bf16x8*)&Ks[hh * 64 + nt * 16 + l15][32 + quad * 8], sv, 0, 0, 0);
            __builtin_amdgcn_s_setprio(0);
#pragma unroll
            for (int r = 0; r < 4; ++r) {
                float e = __builtin_amdgcn_exp2f(bl[r] * sv[r]);
                wv[nt][r] = (!diag || (nt * 16 + l15 <= qrow + r)) ? e : 0.f;
            }
        }
        // P -> wave-private LDS (C-layout write, A-layout read; same-wave)
#pragma unroll
        for (int nt = 0; nt < 4; ++nt)
#pragma unroll
            for (int r = 0; r < 4; ++r)
                Ps[w][quad][r * 72 + nt * 16 + l15] = f2b_fast(wv[nt][r]);
#pragma unroll
        for (int r = 0; r < 4; ++r)
            zp[r] += (wv[0][r] + wv[1][r]) + (wv[2][r] + wv[3][r]);

        bf16x8 pa0 = *(const bf16x8*)&Ps[w][l15 >> 2][(l15 & 3) * 72 + quad * 8];
        bf16x8 pa1 = *(const bf16x8*)&Ps[w][l15 >> 2][(l15 & 3) * 72 + 32 + quad * 8];
#pragma unroll
        for (int nt = 0; nt < 4; ++nt) {
            __builtin_amdgcn_s_setprio(1);
            ov[nt] = __builtin_amdgcn_mfma_f32_16x16x32_bf16(pa0, *(const bf16x8*)&Vs[nt * 16 + l15][hh * 64 + quad * 8], ov[nt], 0, 0, 0);
            ov[nt] = __builtin_amdgcn_mfma_f32_16x16x32_bf16(pa1, *(const bf16x8*)&Vs[nt * 16 + l15][hh * 64 + 32 + quad * 8], ov[nt], 0, 0, 0);
            __builtin_amdgcn_s_setprio(0);
        }
    };

    k0 = *(const uint4*)KS;
    k1 = *(const uint4*)(KS + 32 * HD_);
    k2 = *(const uint4*)(KS + 64 * HD_);
    k3 = *(const uint4*)(KS + 96 * HD_);
    uint4 v0 = *(const uint4*)VS;
    uint4 v1 = *(const uint4*)(VS + 16 * N_);
    uint4 v2 = *(const uint4*)(VS + 32 * N_);
    uint4 v3 = *(const uint4*)(VS + 48 * N_);

    const int nFull = qt >> 1;          // chunks with both halves unmasked
    for (int c = 0; c < nFull; ++c) {
        __syncthreads();
        *(uint4*)&Ks[skey][skc]      = k0;
        *(uint4*)&Ks[32 + skey][skc] = k1;
        *(uint4*)&Ks[64 + skey][skc] = k2;
        *(uint4*)&Ks[96 + skey][skc] = k3;
        *(uint4*)&Vs[vhd][vkc]       = v0;
        *(uint4*)&Vs[16 + vhd][vkc]  = v1;
        *(uint4*)&Vs[32 + vhd][vkc]  = v2;
        *(uint4*)&Vs[48 + vhd][vkc]  = v3;
        __syncthreads();
        {   // prefetch chunk c+1 (always exists: c+1 <= nFull = nCh-1)
            const ushort* nk = KS + (size_t)(c + 1) * (128 * HD_);
            k0 = *(const uint4*)nk;
            k1 = *(const uint4*)(nk + 32 * HD_);
            k2 = *(const uint4*)(nk + 64 * HD_);
            k3 = *(const uint4*)(nk + 96 * HD_);
            const ushort* nv = VS + (c + 1) * 128;
            v0 = *(const uint4*)nv;
            v1 = *(const uint4*)(nv + 16 * N_);
            v2 = *(const uint4*)(nv + 32 * N_);
            v3 = *(const uint4*)(nv + 48 * N_);
        }
        do_half(0, false);
        do_half(1, false);
    }
    // final chunk: diagonal half (+ preceding unmasked half if qt odd)
    __syncthreads();
    *(uint4*)&Ks[skey][skc]      = k0;
    *(uint4*)&Ks[32 + skey][skc] = k1;
    *(uint4*)&Ks[64 + skey][skc] = k2;
    *(uint4*)&Ks[96 + skey][skc] = k3;
    *(uint4*)&Vs[vhd][vkc]       = v0;
    *(uint4*)&Vs[16 + vhd][vkc]  = v1;
    *(uint4*)&Vs[32 + vhd][vkc]  = v2;
    *(uint4*)&Vs[48 + vhd][vkc]  = v3;
    __syncthreads();
    if (qt & 1) {
        do_half(0, false);
        do_half(1, true);
    } else {
        do_half(0, true);
    }

    // hoisted Z' butterfly
#pragma unroll
    for (int r = 0; r < 4; ++r)
#pragma unroll
        for (int off = 1; off < 16; off <<= 1) zp[r] += __shfl_xor(zp[r], off);

    // ---------------- write AO [B, N, D] bf16 ----------------
#pragma unroll
    for (int r = 0; r < 4; ++r) {
        int qg = qt * 64 + w * 16 + quad * 4 + r;
        float inv = 1.f / zp[r];
        size_t rowoff = ((size_t)(b * N_ + qg)) * D_ + h * HD_;
#pragma unroll
        for (int nt = 0; nt < 4; ++nt)
            AO[rowoff + nt * 16 + l15] = f2b(ov[nt][r] * inv);
    }
}

// ---------------------------------------------------------------------------
extern "C" void kernel_launch(void* const* d_in, const int* in_sizes, int n_in,
                              void* d_out, int out_size, void* d_ws, size_t ws_size,
                              hipStream_t stream)
{
    const float* x  = (const float*)d_in[0];
    const float* Wq = (const float*)d_in[1];
    const float* Wk = (const float*)d_in[2];
    const float* Wv = (const float*)d_in[3];
    const float* Wo = (const float*)d_in[4];
    const float* bo = (const float*)d_in[5];
    float* out = (float*)d_out;

    ushort* ws  = (ushort*)d_ws;
    ushort* xb  = ws;                       // 4096*1024
    ushort* wqb = ws + 4194304;             // 1024*1024 each
    ushort* wkb = ws + 5242880;
    ushort* wvb = ws + 6291456;
    ushort* wob = ws + 7340032;
    ushort* Qb  = ws + 8388608;             // [32][2048][64]
    ushort* Kb  = ws + 12582912;            // [32][2048][64]
    ushort* Vtb = ws + 16777216;            // [32][64][2048]  (transposed V)
    ushort* aob = ws + 20971520;            // 4096*1024

    cvt_all<<<8192, 256, 0, stream>>>(x, Wq, Wk, Wv, Wo, xb);

    gemm_qkv<<<dim3(32, 8, 3), 256, 0, stream>>>(
        xb, wqb, wkb, wvb, Qb, Kb, Vtb);

    attn_mfma<<<dim3(1024), 256, 0, stream>>>(Qb, Kb, Vtb, aob);

    gemm_fin<<<dim3(32, 16), 256, 0, stream>>>(aob, wob, bo, out);
}

// Round 14
// 188.533 us; speedup vs baseline: 1.2495x; 1.0118x over previous
//
#include <hip/hip_runtime.h>
#include <math.h>

#define B_   2
#define N_   2048
#define D_   1024
#define H_   16
#define HD_  64
#define BH_  32
#define M_   4096   // B_*N_

typedef __bf16 bf16x8 __attribute__((ext_vector_type(8)));
typedef float  f32x4  __attribute__((ext_vector_type(4)));

__device__ inline unsigned short f2b(float f) {
    unsigned u = __float_as_uint(f);
    u += 0x7FFFu + ((u >> 16) & 1u);
    return (unsigned short)(u >> 16);
}
// cheap round (1 ulp vs RNE on ties; P has huge margin)
__device__ inline unsigned short f2b_fast(float f) {
    return (unsigned short)((__float_as_uint(f) + 0x8000u) >> 16);
}

// ---------------------------------------------------------------------------
// Convert x (4096x1024) and Wq/Wk/Wv/Wo (1024x1024 each) fp32 -> bf16 into one
// contiguous ws region: [x | wq | wk | wv | wo].
// ---------------------------------------------------------------------------
__global__ __launch_bounds__(256)
void cvt_all(const float* __restrict__ x,  const float* __restrict__ wq,
             const float* __restrict__ wk, const float* __restrict__ wv,
             const float* __restrict__ wo, ushort* __restrict__ dst)
{
    int i = blockIdx.x * 256 + threadIdx.x;      // float4 index
    if (i >= 2097152) return;                    // (4096*1024 + 4*1024*1024)/4
    int fi = i * 4;
    const float* s; int off;
    if (fi < 4194304) { s = x; off = fi; }
    else {
        int r = fi - 4194304;
        int wsel = r >> 20;                      // each W = 2^20 elements
        off = r & 1048575;
        s = (wsel == 0) ? wq : (wsel == 1) ? wk : (wsel == 2) ? wv : wo;
    }
    float4 f = *(const float4*)(s + off);
    ushort4 o;
    o.x = f2b(f.x); o.y = f2b(f.y); o.z = f2b(f.z); o.w = f2b(f.w);
    *(ushort4*)(dst + fi) = o;
}

// ---------------------------------------------------------------------------
// QKV bf16 MFMA GEMM — R21-verified winner: BK=64, 128x128 tile, 4 waves 2x2,
// reg-prefetch 2-barrier path, 16 barrier-pairs.  LDS [128][72]x2 = 36.9 KB,
// 3 blocks/CU.  Total 199.9->190.1 in R11.  Do not modify.
// z=0 (Q): scaled by 0.125*log2e (exp2-domain softmax) -> [BH][N][64]
// z=1 (K): [BH][N][64];  z=2 (V): TRANSPOSED [BH][HD][N] (ushort4 stores).
// ---------------------------------------------------------------------------
__global__ __launch_bounds__(256)
void gemm_qkv(const ushort* __restrict__ A,
              const ushort* __restrict__ W0, const ushort* __restrict__ W1,
              const ushort* __restrict__ W2,
              ushort* __restrict__ O0, ushort* __restrict__ O1,
              ushort* __restrict__ O2)
{
    const int z = blockIdx.z;
    const ushort* W = (z == 0) ? W0 : (z == 1) ? W1 : W2;

    __shared__ alignas(16) ushort As[128][72];
    __shared__ alignas(16) ushort Bs[128][72];

    const int t = threadIdx.x;
    const int lane = t & 63, w = t >> 6;
    const int quad = lane >> 4, l15 = lane & 15;
    const int wm = (w >> 1) * 64, wn = (w & 1) * 64;
    const int tileM = blockIdx.x * 128, tileN = blockIdx.y * 128;

    // staging map: rows srow + {0,32,64,96}, ushort cols scol..scol+7
    const int srow = t >> 3;             // 0..31
    const int scol = (t & 7) * 8;        // 0..56
    const ushort* GA = A + (size_t)(tileM + srow) * D_ + scol;
    const ushort* GB = W + (size_t)(tileN + srow) * D_ + scol;

    f32x4 acc[4][4];
#pragma unroll
    for (int mt = 0; mt < 4; ++mt)
#pragma unroll
        for (int nt = 0; nt < 4; ++nt) acc[mt][nt] = (f32x4){0.f, 0.f, 0.f, 0.f};

    uint4 pa0 = *(const uint4*)GA;
    uint4 pa1 = *(const uint4*)(GA + 32 * D_);
    uint4 pa2 = *(const uint4*)(GA + 64 * D_);
    uint4 pa3 = *(const uint4*)(GA + 96 * D_);
    uint4 pb0 = *(const uint4*)GB;
    uint4 pb1 = *(const uint4*)(GB + 32 * D_);
    uint4 pb2 = *(const uint4*)(GB + 64 * D_);
    uint4 pb3 = *(const uint4*)(GB + 96 * D_);

    for (int k0 = 0; k0 < D_; k0 += 64) {
        __syncthreads();                 // prev tile's readers done
        *(uint4*)&As[srow][scol]      = pa0;
        *(uint4*)&As[32 + srow][scol] = pa1;
        *(uint4*)&As[64 + srow][scol] = pa2;
        *(uint4*)&As[96 + srow][scol] = pa3;
        *(uint4*)&Bs[srow][scol]      = pb0;
        *(uint4*)&Bs[32 + srow][scol] = pb1;
        *(uint4*)&Bs[64 + srow][scol] = pb2;
        *(uint4*)&Bs[96 + srow][scol] = pb3;
        __syncthreads();
        if (k0 + 64 < D_) {              // prefetch next tile (used next iter)
            pa0 = *(const uint4*)(GA + k0 + 64);
            pa1 = *(const uint4*)(GA + 32 * D_ + k0 + 64);
            pa2 = *(const uint4*)(GA + 64 * D_ + k0 + 64);
            pa3 = *(const uint4*)(GA + 96 * D_ + k0 + 64);
            pb0 = *(const uint4*)(GB + k0 + 64);
            pb1 = *(const uint4*)(GB + 32 * D_ + k0 + 64);
            pb2 = *(const uint4*)(GB + 64 * D_ + k0 + 64);
            pb3 = *(const uint4*)(GB + 96 * D_ + k0 + 64);
        }

#pragma unroll
        for (int ks = 0; ks < 2; ++ks) {
            bf16x8 af[4], bf[4];
#pragma unroll
            for (int mt = 0; mt < 4; ++mt) af[mt] = *(const bf16x8*)&As[wm + mt * 16 + l15][ks * 32 + quad * 8];
#pragma unroll
            for (int nt = 0; nt < 4; ++nt) bf[nt] = *(const bf16x8*)&Bs[wn + nt * 16 + l15][ks * 32 + quad * 8];
#pragma unroll
            for (int mt = 0; mt < 4; ++mt)
#pragma unroll
                for (int nt = 0; nt < 4; ++nt)
                    acc[mt][nt] = __builtin_amdgcn_mfma_f32_16x16x32_bf16(af[mt], bf[nt], acc[mt][nt], 0, 0, 0);
        }
    }

    ushort* O = (z == 0) ? O0 : (z == 1) ? O1 : O2;
    // Q: fold 1/sqrt(64) AND log2e (exp2-domain softmax) into the scale
    const float scl = (z == 0) ? 0.18033688f : 1.0f;
#pragma unroll
    for (int mt = 0; mt < 4; ++mt)
#pragma unroll
        for (int nt = 0; nt < 4; ++nt) {
            if (z == 2) {
                // V transposed: Vt[bh][dd][n], 4 consecutive n per 8B store
                int rg0 = tileM + wm + mt * 16 + quad * 4;
                int cgc = tileN + wn + nt * 16 + l15;
                int b = rg0 >> 11, n0 = rg0 & (N_ - 1);
                int h = cgc >> 6, dd = cgc & 63;
                ushort4 o4;
                o4.x = f2b(acc[mt][nt][0]); o4.y = f2b(acc[mt][nt][1]);
                o4.z = f2b(acc[mt][nt][2]); o4.w = f2b(acc[mt][nt][3]);
                *(ushort4*)&O[((size_t)((b * H_ + h) * HD_ + dd)) * N_ + n0] = o4;
            } else {
#pragma unroll
                for (int r = 0; r < 4; ++r) {
                    int rg = tileM + wm + mt * 16 + quad * 4 + r;
                    int cgc = tileN + wn + nt * 16 + l15;
                    int b = rg >> 11, n = rg & (N_ - 1);
                    int h = cgc >> 6, dd = cgc & 63;
                    O[(((size_t)(b * H_ + h)) * N_ + n) * HD_ + dd] = f2b(acc[mt][nt][r] * scl);
                }
            }
        }
}

// ---------------------------------------------------------------------------
// Final GEMM — R24: BK=128 retry with NAMED SCALARS.  R22's theory (fin is
// grid-capped at 2 blocks/CU; LDS headroom buys no occupancy -> spend on
// K-depth, 8 barrier-pairs instead of 16) was sound; its implementation
// failed because uint4 pa[8]/pb[4] ARRAYS went to scratch (VGPR 68 +
// WRITE_SIZE 150 MB = spill signature; rule #20 / SROA on 192B aggregate).
// Fix: 12 individual named uint4 (SSA values, cannot be allocated in local
// memory — qkv holds 8 the same way at VGPR 80, no spill).
// LDS As[128][136]+Bs[64][136] = 52.2 KB, 2 blocks/CU unchanged.
// Staging: rows t>>4 + j*16, cols (t&15)*8 (coalesced 256B rows); [136]
// stride -> ds ops at +4 banks = free 2-way.
// ---------------------------------------------------------------------------
__global__ __launch_bounds__(256)
void gemm_fin(const ushort* __restrict__ A, const ushort* __restrict__ W,
              const float* __restrict__ bias, float* __restrict__ Of)
{
    __shared__ alignas(16) ushort As[128][136];
    __shared__ alignas(16) ushort Bs[64][136];

    const int t = threadIdx.x;
    const int lane = t & 63, w = t >> 6;
    const int quad = lane >> 4, l15 = lane & 15;
    const int wm = (w >> 1) * 64, wn = (w & 1) * 32;
    const int tileM = blockIdx.x * 128, tileN = blockIdx.y * 64;

    const int srow = t >> 4;             // 0..15
    const int scol = (t & 15) * 8;       // 0..120
    const ushort* GA = A + (size_t)(tileM + srow) * D_ + scol;
    const ushort* GB = W + (size_t)(tileN + srow) * D_ + scol;

    f32x4 acc[4][2];
#pragma unroll
    for (int mt = 0; mt < 4; ++mt)
#pragma unroll
        for (int nt = 0; nt < 2; ++nt) acc[mt][nt] = (f32x4){0.f, 0.f, 0.f, 0.f};

    uint4 pa0 = *(const uint4*)GA;
    uint4 pa1 = *(const uint4*)(GA + 16 * D_);
    uint4 pa2 = *(const uint4*)(GA + 32 * D_);
    uint4 pa3 = *(const uint4*)(GA + 48 * D_);
    uint4 pa4 = *(const uint4*)(GA + 64 * D_);
    uint4 pa5 = *(const uint4*)(GA + 80 * D_);
    uint4 pa6 = *(const uint4*)(GA + 96 * D_);
    uint4 pa7 = *(const uint4*)(GA + 112 * D_);
    uint4 pb0 = *(const uint4*)GB;
    uint4 pb1 = *(const uint4*)(GB + 16 * D_);
    uint4 pb2 = *(const uint4*)(GB + 32 * D_);
    uint4 pb3 = *(const uint4*)(GB + 48 * D_);

    for (int k0 = 0; k0 < D_; k0 += 128) {
        __syncthreads();
        *(uint4*)&As[srow][scol]       = pa0;
        *(uint4*)&As[16 + srow][scol]  = pa1;
        *(uint4*)&As[32 + srow][scol]  = pa2;
        *(uint4*)&As[48 + srow][scol]  = pa3;
        *(uint4*)&As[64 + srow][scol]  = pa4;
        *(uint4*)&As[80 + srow][scol]  = pa5;
        *(uint4*)&As[96 + srow][scol]  = pa6;
        *(uint4*)&As[112 + srow][scol] = pa7;
        *(uint4*)&Bs[srow][scol]       = pb0;
        *(uint4*)&Bs[16 + srow][scol]  = pb1;
        *(uint4*)&Bs[32 + srow][scol]  = pb2;
        *(uint4*)&Bs[48 + srow][scol]  = pb3;
        __syncthreads();
        if (k0 + 128 < D_) {
            pa0 = *(const uint4*)(GA + k0 + 128);
            pa1 = *(const uint4*)(GA + 16 * D_ + k0 + 128);
            pa2 = *(const uint4*)(GA + 32 * D_ + k0 + 128);
            pa3 = *(const uint4*)(GA + 48 * D_ + k0 + 128);
            pa4 = *(const uint4*)(GA + 64 * D_ + k0 + 128);
            pa5 = *(const uint4*)(GA + 80 * D_ + k0 + 128);
            pa6 = *(const uint4*)(GA + 96 * D_ + k0 + 128);
            pa7 = *(const uint4*)(GA + 112 * D_ + k0 + 128);
            pb0 = *(const uint4*)(GB + k0 + 128);
            pb1 = *(const uint4*)(GB + 16 * D_ + k0 + 128);
            pb2 = *(const uint4*)(GB + 32 * D_ + k0 + 128);
            pb3 = *(const uint4*)(GB + 48 * D_ + k0 + 128);
        }

#pragma unroll
        for (int ks = 0; ks < 4; ++ks) {
            bf16x8 af[4], bf[2];
#pragma unroll
            for (int mt = 0; mt < 4; ++mt) af[mt] = *(const bf16x8*)&As[wm + mt * 16 + l15][ks * 32 + quad * 8];
#pragma unroll
            for (int nt = 0; nt < 2; ++nt) bf[nt] = *(const bf16x8*)&Bs[wn + nt * 16 + l15][ks * 32 + quad * 8];
#pragma unroll
            for (int mt = 0; mt < 4; ++mt)
#pragma unroll
                for (int nt = 0; nt < 2; ++nt)
                    acc[mt][nt] = __builtin_amdgcn_mfma_f32_16x16x32_bf16(af[mt], bf[nt], acc[mt][nt], 0, 0, 0);
        }
    }

#pragma unroll
    for (int mt = 0; mt < 4; ++mt)
#pragma unroll
        for (int nt = 0; nt < 2; ++nt)
#pragma unroll
            for (int r = 0; r < 4; ++r) {
                int rg = tileM + wm + mt * 16 + quad * 4 + r;
                int cgc = tileN + wn + nt * 16 + l15;
                Of[(size_t)rg * D_ + cgc] = acc[mt][nt][r] + bias[cgc];
            }
}

// ---------------------------------------------------------------------------
// MFMA adaptive-temperature causal flash attention — R3/R20 BYTE-EXACT.
// Verified anchor (63.1-65.0 us).  Every structural variant regressed
// (R4 224, R5 100, R6 91, R7 92, R8 77, R19 69.5).  Do not modify.
// ---------------------------------------------------------------------------
__global__ __launch_bounds__(256)
void attn_mfma(const ushort* __restrict__ Q, const ushort* __restrict__ K,
               const ushort* __restrict__ VT, ushort* __restrict__ AO)
{
    const int bid = blockIdx.x;
    const int qt = 31 - (bid >> 5);     // LPT: heavy q-tiles first
    const int bh = bid & 31;            // bh minor: XCD L2 locality
    const size_t kvbase = (size_t)bh * N_ * HD_;

    __shared__ alignas(16) ushort Ks[128][72];      // [key][hd], 128 keys/stage
    __shared__ alignas(16) ushort Vs[64][136];      // [hd][key], 128 keys + pad
    __shared__ alignas(16) ushort Ps[4][4][296];    // wave-private P, grp-padded

    const int t = threadIdx.x;
    const int lane = t & 63, w = t >> 6;
    const int quad = lane >> 4, l15 = lane & 15;
    const float SH2 = 11.5416913f;     // 8 * log2(e)
    const float LN2 = 0.69314718f;

    // K staging: thread covers rows skey+{0,32,64,96} of the 128-key chunk
    const int skey = t >> 3;            // 0..31
    const int skc  = (t & 7) * 8;       // 0..56
    const ushort* KS = K + kvbase + (size_t)skey * HD_ + skc;   // + key*HD_
    // V staging: thread covers hd rows vhd+{0,16,32,48}, key-cols vkc..vkc+7
    const int vhd = t >> 4;             // 0..15
    const int vkc = (t & 15) * 8;       // 0..120
    const ushort* VS = VT + kvbase + (size_t)vhd * N_ + vkc;    // + chunkbase

    const int qrow = w * 16 + quad * 4;
    const int b = bh >> 4, h = bh & 15;
    const int nCh = (qt + 2) >> 1;      // 128-key chunks (last may be half-used)

    // Q fragments (registers all kernel)
    bf16x8 aq0, aq1;
    {
        const size_t qr = kvbase + (size_t)(qt * 64 + w * 16 + l15) * HD_;
        aq0 = *(const bf16x8*)&Q[qr + quad * 8];
        aq1 = *(const bf16x8*)&Q[qr + 32 + quad * 8];
    }

    float ez[4] = {0.f, 0.f, 0.f, 0.f};
    float sz[4] = {0.f, 0.f, 0.f, 0.f};

    // unmasked pass-1 score tile: accumulate Z, S2
    auto p1_tile = [&](const int nt) {
        f32x4 sv = (f32x4){-SH2, -SH2, -SH2, -SH2};   // C-init: -SH2 rides free
        __builtin_amdgcn_s_setprio(1);
        sv = __builtin_amdgcn_mfma_f32_16x16x32_bf16(aq0, *(const bf16x8*)&Ks[nt * 16 + l15][quad * 8], sv, 0, 0, 0);
        sv = __builtin_amdgcn_mfma_f32_16x16x32_bf16(aq1, *(const bf16x8*)&Ks[nt * 16 + l15][32 + quad * 8], sv, 0, 0, 0);
        __builtin_amdgcn_s_setprio(0);
#pragma unroll
        for (int r = 0; r < 4; ++r) {
            float sh = sv[r];
            float e = __builtin_amdgcn_exp2f(sh);
            ez[r] += e;
            sz[r] = fmaf(e, sh, sz[r]);
        }
    };
    // masked pass-1 tile: j = 16-key offset within the diagonal 64-key block
    auto p1_tile_mask = [&](const int nt, const int j) {
        f32x4 sv = (f32x4){-SH2, -SH2, -SH2, -SH2};
        __builtin_amdgcn_s_setprio(1);
        sv = __builtin_amdgcn_mfma_f32_16x16x32_bf16(aq0, *(const bf16x8*)&Ks[nt * 16 + l15][quad * 8], sv, 0, 0, 0);
        sv = __builtin_amdgcn_mfma_f32_16x16x32_bf16(aq1, *(const bf16x8*)&Ks[nt * 16 + l15][32 + quad * 8], sv, 0, 0, 0);
        __builtin_amdgcn_s_setprio(0);
        const int kc = j * 16 + l15;
#pragma unroll
        for (int r = 0; r < 4; ++r) {
            float sh = sv[r];
            float e = (kc <= qrow + r) ? __builtin_amdgcn_exp2f(sh) : 0.f;
            ez[r] += e;
            sz[r] = fmaf(e, sh, sz[r]);
        }
    };

    // ---------------- pass 1: Z, S2 (128-key stages) ----------------
    uint4 k0 = *(const uint4*)KS;
    uint4 k1 = *(const uint4*)(KS + 32 * HD_);
    uint4 k2 = *(const uint4*)(KS + 64 * HD_);
    uint4 k3 = *(const uint4*)(KS + 96 * HD_);
    const int nF1 = nCh - 1;            // fully-unmasked chunks
    for (int c = 0; c < nF1; ++c) {
        __syncthreads();
        *(uint4*)&Ks[skey][skc]      = k0;
        *(uint4*)&Ks[32 + skey][skc] = k1;
        *(uint4*)&Ks[64 + skey][skc] = k2;
        *(uint4*)&Ks[96 + skey][skc] = k3;
        __syncthreads();
        {   // prefetch chunk c+1 (always exists: c+1 <= nCh-1)
            const ushort* nb = KS + (size_t)(c + 1) * (128 * HD_);
            k0 = *(const uint4*)nb;
            k1 = *(const uint4*)(nb + 32 * HD_);
            k2 = *(const uint4*)(nb + 64 * HD_);
            k3 = *(const uint4*)(nb + 96 * HD_);
        }
#pragma unroll
        for (int nt = 0; nt < 8; ++nt) p1_tile(nt);
    }
    // final chunk: qt odd -> 4 unmasked + 4 masked tiles; qt even -> 4 masked
    __syncthreads();
    *(uint4*)&Ks[skey][skc]      = k0;
    *(uint4*)&Ks[32 + skey][skc] = k1;
    *(uint4*)&Ks[64 + skey][skc] = k2;
    *(uint4*)&Ks[96 + skey][skc] = k3;
    __syncthreads();
    if (qt & 1) {
#pragma unroll
        for (int nt = 0; nt < 4; ++nt) p1_tile(nt);
#pragma unroll
        for (int j = 0; j < 4; ++j) p1_tile_mask(4 + j, j);
    } else {
#pragma unroll
        for (int j = 0; j < 4; ++j) p1_tile_mask(j, j);
    }

    // hoisted 16-lane butterfly reduce
#pragma unroll
    for (int r = 0; r < 4; ++r) {
#pragma unroll
        for (int off = 1; off < 16; off <<= 1) {
            ez[r] += __shfl_xor(ez[r], off);
            sz[r] += __shfl_xor(sz[r], off);
        }
    }

    // ---------------- entropy -> beta ----------------
    float bl[4];   // w = exp2(beta * (s2 - SH2))  (sv carries -SH2)
#pragma unroll
    for (int r = 0; r < 4; ++r) {
        float Z = ez[r];
        float Hh = LN2 * (__builtin_amdgcn_logf(Z) - sz[r] / Z);
        float bb = 1.f;
        if (Hh > 0.5f) {
            float e2 = Hh * Hh;
            float pp = -0.037f * e2 * e2 + 0.481f * e2 * Hh - 2.3f * e2 + 4.917f * Hh - 1.791f;
            bb = fmaxf(pp, 1.f);
        }
        bl[r] = bb;
    }

    // ---------------- pass 2: O, Z' (128-key stages, two 64-key halves) -----
    f32x4 ov[4];
#pragma unroll
    for (int nt = 0; nt < 4; ++nt) ov[nt] = (f32x4){0.f, 0.f, 0.f, 0.f};
    float zp[4] = {0.f, 0.f, 0.f, 0.f};

    // one 64-key half: QK^T -> weights -> P round-trip -> PV
    auto do_half = [&](const int hh, const bool diag) {
        float wv[4][4];
#pragma unroll
        for (int nt = 0; nt < 4; ++nt) {
            f32x4 sv = (f32x4){-SH2, -SH2, -SH2, -SH2};   // C-init: -SH2
            __builtin_amdgcn_s_setprio(1);
            sv = __builtin_amdgcn_mfma_f32_16x16x32_bf16(aq0, *(const bf16x8*)&Ks[hh * 64 + nt * 16 + l15][quad * 8], sv, 0, 0, 0);
            sv = __builtin_amdgcn_mfma_f32_16x16x32_bf16(aq1, *(const bf16x8*)&Ks[hh * 64 + nt * 16 + l15][32 + quad * 8], sv, 0, 0, 0);
            __builtin_amdgcn_s_setprio(0);
#pragma unroll
            for (int r = 0; r < 4; ++r) {
                float e = __builtin_amdgcn_exp2f(bl[r] * sv[r]);
                wv[nt][r] = (!diag || (nt * 16 + l15 <= qrow + r)) ? e : 0.f;
            }
        }
        // P -> wave-private LDS (C-layout write, A-layout read; same-wave)
#pragma unroll
        for (int nt = 0; nt < 4; ++nt)
#pragma unroll
            for (int r = 0; r < 4; ++r)
                Ps[w][quad][r * 72 + nt * 16 + l15] = f2b_fast(wv[nt][r]);
#pragma unroll
        for (int r = 0; r < 4; ++r)
            zp[r] += (wv[0][r] + wv[1][r]) + (wv[2][r] + wv[3][r]);

        bf16x8 pa0 = *(const bf16x8*)&Ps[w][l15 >> 2][(l15 & 3) * 72 + quad * 8];
        bf16x8 pa1 = *(const bf16x8*)&Ps[w][l15 >> 2][(l15 & 3) * 72 + 32 + quad * 8];
#pragma unroll
        for (int nt = 0; nt < 4; ++nt) {
            __builtin_amdgcn_s_setprio(1);
            ov[nt] = __builtin_amdgcn_mfma_f32_16x16x32_bf16(pa0, *(const bf16x8*)&Vs[nt * 16 + l15][hh * 64 + quad * 8], ov[nt], 0, 0, 0);
            ov[nt] = __builtin_amdgcn_mfma_f32_16x16x32_bf16(pa1, *(const bf16x8*)&Vs[nt * 16 + l15][hh * 64 + 32 + quad * 8], ov[nt], 0, 0, 0);
            __builtin_amdgcn_s_setprio(0);
        }
    };

    k0 = *(const uint4*)KS;
    k1 = *(const uint4*)(KS + 32 * HD_);
    k2 = *(const uint4*)(KS + 64 * HD_);
    k3 = *(const uint4*)(KS + 96 * HD_);
    uint4 v0 = *(const uint4*)VS;
    uint4 v1 = *(const uint4*)(VS + 16 * N_);
    uint4 v2 = *(const uint4*)(VS + 32 * N_);
    uint4 v3 = *(const uint4*)(VS + 48 * N_);

    const int nFull = qt >> 1;          // chunks with both halves unmasked
    for (int c = 0; c < nFull; ++c) {
        __syncthreads();
        *(uint4*)&Ks[skey][skc]      = k0;
        *(uint4*)&Ks[32 + skey][skc] = k1;
        *(uint4*)&Ks[64 + skey][skc] = k2;
        *(uint4*)&Ks[96 + skey][skc] = k3;
        *(uint4*)&Vs[vhd][vkc]       = v0;
        *(uint4*)&Vs[16 + vhd][vkc]  = v1;
        *(uint4*)&Vs[32 + vhd][vkc]  = v2;
        *(uint4*)&Vs[48 + vhd][vkc]  = v3;
        __syncthreads();
        {   // prefetch chunk c+1 (always exists: c+1 <= nFull = nCh-1)
            const ushort* nk = KS + (size_t)(c + 1) * (128 * HD_);
            k0 = *(const uint4*)nk;
            k1 = *(const uint4*)(nk + 32 * HD_);
            k2 = *(const uint4*)(nk + 64 * HD_);
            k3 = *(const uint4*)(nk + 96 * HD_);
            const ushort* nv = VS + (c + 1) * 128;
            v0 = *(const uint4*)nv;
            v1 = *(const uint4*)(nv + 16 * N_);
            v2 = *(const uint4*)(nv + 32 * N_);
            v3 = *(const uint4*)(nv + 48 * N_);
        }
        do_half(0, false);
        do_half(1, false);
    }
    // final chunk: diagonal half (+ preceding unmasked half if qt odd)
    __syncthreads();
    *(uint4*)&Ks[skey][skc]      = k0;
    *(uint4*)&Ks[32 + skey][skc] = k1;
    *(uint4*)&Ks[64 + skey][skc] = k2;
    *(uint4*)&Ks[96 + skey][skc] = k3;
    *(uint4*)&Vs[vhd][vkc]       = v0;
    *(uint4*)&Vs[16 + vhd][vkc]  = v1;
    *(uint4*)&Vs[32 + vhd][vkc]  = v2;
    *(uint4*)&Vs[48 + vhd][vkc]  = v3;
    __syncthreads();
    if (qt & 1) {
        do_half(0, false);
        do_half(1, true);
    } else {
        do_half(0, true);
    }

    // hoisted Z' butterfly
#pragma unroll
    for (int r = 0; r < 4; ++r)
#pragma unroll
        for (int off = 1; off < 16; off <<= 1) zp[r] += __shfl_xor(zp[r], off);

    // ---------------- write AO [B, N, D] bf16 ----------------
#pragma unroll
    for (int r = 0; r < 4; ++r) {
        int qg = qt * 64 + w * 16 + quad * 4 + r;
        float inv = 1.f / zp[r];
        size_t rowoff = ((size_t)(b * N_ + qg)) * D_ + h * HD_;
#pragma unroll
        for (int nt = 0; nt < 4; ++nt)
            AO[rowoff + nt * 16 + l15] = f2b(ov[nt][r] * inv);
    }
}

// ---------------------------------------------------------------------------
extern "C" void kernel_launch(void* const* d_in, const int* in_sizes, int n_in,
                              void* d_out, int out_size, void* d_ws, size_t ws_size,
                              hipStream_t stream)
{
    const float* x  = (const float*)d_in[0];
    const float* Wq = (const float*)d_in[1];
    const float* Wk = (const float*)d_in[2];
    const float* Wv = (const float*)d_in[3];
    const float* Wo = (const float*)d_in[4];
    const float* bo = (const float*)d_in[5];
    float* out = (float*)d_out;

    ushort* ws  = (ushort*)d_ws;
    ushort* xb  = ws;                       // 4096*1024
    ushort* wqb = ws + 4194304;             // 1024*1024 each
    ushort* wkb = ws + 5242880;
    ushort* wvb = ws + 6291456;
    ushort* wob = ws + 7340032;
    ushort* Qb  = ws + 8388608;             // [32][2048][64]
    ushort* Kb  = ws + 12582912;            // [32][2048][64]
    ushort* Vtb = ws + 16777216;            // [32][64][2048]  (transposed V)
    ushort* aob = ws + 20971520;            // 4096*1024

    cvt_all<<<8192, 256, 0, stream>>>(x, Wq, Wk, Wv, Wo, xb);

    gemm_qkv<<<dim3(32, 8, 3), 256, 0, stream>>>(
        xb, wqb, wkb, wvb, Qb, Kb, Vtb);

    attn_mfma<<<dim3(1024), 256, 0, stream>>>(Qb, Kb, Vtb, aob);

    gemm_fin<<<dim3(32, 16), 256, 0, stream>>>(aob, wob, bo, out);
}